// Round 6
// baseline (979.520 us; speedup 1.0000x reference)
//
#include <hip/hip_runtime.h>
#include <cstdint>
#include <cfloat>

#define IN_DIM 768
#define HID    1024
#define KSEL   20
#define MAXC   64
#define TARGET 24
#define WSCALE 4096.0f
#define INV_WSCALE (1.0f / 4096.0f)
#define DELTA  3e-5f

typedef _Float16 f16x8 __attribute__((ext_vector_type(8)));
typedef float    f32x4 __attribute__((ext_vector_type(4)));

__device__ __forceinline__ void gload_lds16(const void* g, void* l) {
    __builtin_amdgcn_global_load_lds(
        (const __attribute__((address_space(1))) uint32_t*)g,
        (__attribute__((address_space(3))) uint32_t*)l, 16, 0, 0);
}

// ---------------- K0: transpose W_dec [768][1024] -> WdTb [1024][768] bf16 (RNE) ----------------
__global__ void k_prep_wdb(const float* __restrict__ Wd, ushort* __restrict__ WdTb) {
    __shared__ float tile[32][33];
    const int j0 = blockIdx.x * 32;       // along HID
    const int i0 = blockIdx.y * 32;       // along IN_DIM
    const int tx = threadIdx.x;
    const int ty = threadIdx.y;
#pragma unroll
    for (int r = 0; r < 4; ++r)
        tile[ty + r * 8][tx] = Wd[(size_t)(i0 + ty + r * 8) * HID + (j0 + tx)];
    __syncthreads();
#pragma unroll
    for (int r = 0; r < 4; ++r) {
        const float v = tile[tx][ty + r * 8];
        uint u = __float_as_uint(v);
        u += 0x7FFFu + ((u >> 16) & 1u);           // round-to-nearest-even
        WdTb[(size_t)(j0 + ty + r * 8) * IN_DIM + (i0 + tx)] = (ushort)(u >> 16);
    }
}

// ---------------- fallback fp32 transpose (small-ws path keeps old gather) ----------------
__global__ void k_transpose(const float* __restrict__ Wd, float* __restrict__ WdT) {
    __shared__ float tile[32][33];
    const int j0 = blockIdx.x * 32;
    const int i0 = blockIdx.y * 32;
    const int tx = threadIdx.x;
    const int ty = threadIdx.y;
#pragma unroll
    for (int r = 0; r < 4; ++r)
        tile[ty + r * 8][tx] = Wd[(size_t)(i0 + ty + r * 8) * HID + (j0 + tx)];
    __syncthreads();
#pragma unroll
    for (int r = 0; r < 4; ++r)
        WdT[(size_t)(j0 + ty + r * 8) * IN_DIM + (i0 + tx)] = tile[tx][ty + r * 8];
}

// ---------------- split kernels: fp32 -> fp16 (W scaled by 4096) ----------------
__global__ __launch_bounds__(256) void k_split_x(const float* __restrict__ x,
                                                 _Float16* __restrict__ xh) {
    const size_t base = ((size_t)blockIdx.x * 256 + threadIdx.x) * 8;
    const float4 a = *(const float4*)(x + base);
    const float4 b = *(const float4*)(x + base + 4);
    f16x8 o;
    o[0] = (_Float16)a.x; o[1] = (_Float16)a.y; o[2] = (_Float16)a.z; o[3] = (_Float16)a.w;
    o[4] = (_Float16)b.x; o[5] = (_Float16)b.y; o[6] = (_Float16)b.z; o[7] = (_Float16)b.w;
    *(f16x8*)(xh + base) = o;
}

__global__ __launch_bounds__(256) void k_split_w(const float* __restrict__ w,
                                                 _Float16* __restrict__ wh) {
    const size_t base = ((size_t)blockIdx.x * 256 + threadIdx.x) * 8;
    const float4 a = *(const float4*)(w + base);
    const float4 b = *(const float4*)(w + base + 4);
    f16x8 o;
    o[0] = (_Float16)(a.x * WSCALE); o[1] = (_Float16)(a.y * WSCALE);
    o[2] = (_Float16)(a.z * WSCALE); o[3] = (_Float16)(a.w * WSCALE);
    o[4] = (_Float16)(b.x * WSCALE); o[5] = (_Float16)(b.y * WSCALE);
    o[6] = (_Float16)(b.z * WSCALE); o[7] = (_Float16)(b.w * WSCALE);
    *(f16x8*)(wh + base) = o;
}

// ---------------- K1: fp16 MFMA encode  h = relu((x16 @ w16^T)/4096 + be) ----------------
__global__ __launch_bounds__(256) void k_encode_f16(
    const _Float16* __restrict__ xh, const _Float16* __restrict__ wh,
    const float* __restrict__ be, float* __restrict__ h)
{
    __shared__ _Float16 lA[128 * 64];
    __shared__ _Float16 lB[128 * 64];
    const int t   = threadIdx.x;
    const int wid = t >> 6, l = t & 63;
    const int wm  = (wid >> 1) * 64, wn = (wid & 1) * 64;
    const int bn  = blockIdx.x * 128, bm = blockIdx.y * 128;

    const int lr = l >> 3;
    const int sl = (l & 7) ^ lr;
    const _Float16* gA = xh + (size_t)(bm + wid * 32 + lr) * IN_DIM + sl * 8;
    const _Float16* gB = wh + (size_t)(bn + wid * 32 + lr) * IN_DIM + sl * 8;
    char* la0 = (char*)lA + wid * 32 * 128;
    char* lb0 = (char*)lB + wid * 32 * 128;

    f32x4 acc[4][4];
#pragma unroll
    for (int i = 0; i < 4; ++i)
#pragma unroll
        for (int j = 0; j < 4; ++j) acc[i][j] = (f32x4){0.f, 0.f, 0.f, 0.f};

    const int row16 = l & 15, kb = l >> 4;

    for (int kt = 0; kt < IN_DIM; kt += 64) {
        __syncthreads();
#pragma unroll
        for (int i = 0; i < 4; ++i) {
            gload_lds16(gA + (size_t)i * 8 * IN_DIM + kt, la0 + i * 1024);
            gload_lds16(gB + (size_t)i * 8 * IN_DIM + kt, lb0 + i * 1024);
        }
        __syncthreads();

        f16x8 af[4][2], bf[4][2];
#pragma unroll
        for (int f = 0; f < 4; ++f) {
            const int ra = wm + f * 16 + row16;
            const int pa = kb ^ (ra & 7);
            af[f][0] = *(const f16x8*)((const char*)lA + ra * 128 + pa * 16);
            af[f][1] = *(const f16x8*)((const char*)lA + ra * 128 + (pa ^ 4) * 16);
            const int rb = wn + f * 16 + row16;
            const int pb = kb ^ (rb & 7);
            bf[f][0] = *(const f16x8*)((const char*)lB + rb * 128 + pb * 16);
            bf[f][1] = *(const f16x8*)((const char*)lB + rb * 128 + (pb ^ 4) * 16);
        }
#pragma unroll
        for (int kh = 0; kh < 2; ++kh)
#pragma unroll
            for (int fm = 0; fm < 4; ++fm)
#pragma unroll
                for (int fn = 0; fn < 4; ++fn)
                    acc[fm][fn] = __builtin_amdgcn_mfma_f32_16x16x32_f16(
                        af[fm][kh], bf[fn][kh], acc[fm][fn], 0, 0, 0);
    }

    const int col = l & 15, rg = (l >> 4) * 4;
#pragma unroll
    for (int fn = 0; fn < 4; ++fn) {
        const int n = bn + wn + fn * 16 + col;
        const float bias = be[n];
#pragma unroll
        for (int fm = 0; fm < 4; ++fm) {
            const int m0 = bm + wm + fm * 16 + rg;
#pragma unroll
            for (int q = 0; q < 4; ++q)
                h[(size_t)(m0 + q) * HID + n] = fmaxf(fmaf(acc[fm][fn][q], INV_WSCALE, bias), 0.f);
        }
    }
}

// ---------------- K1-fallback: fp32 encode ----------------
__global__ __launch_bounds__(256, 2) void k_encode(
    const float* __restrict__ x, const float* __restrict__ We,
    const float* __restrict__ be, float* __restrict__ h)
{
    __shared__ float lx[16][132];
    __shared__ float lw[16][132];
    const int t  = threadIdx.x;
    const int tx = t & 15;
    const int ty = t >> 4;
    const int bn = blockIdx.x * 128;
    const int bm = blockIdx.y * 128;

    float acc[8][8];
#pragma unroll
    for (int r = 0; r < 8; ++r)
#pragma unroll
        for (int c = 0; c < 8; ++c) acc[r][c] = 0.f;

    const int sk = t & 15;
    const int sm = t >> 4;

    for (int kt = 0; kt < IN_DIM; kt += 16) {
        __syncthreads();
#pragma unroll
        for (int p = 0; p < 8; ++p) {
            const int m = sm + p * 16;
            lx[sk][m] = x [(size_t)(bm + m) * IN_DIM + (kt + sk)];
            lw[sk][m] = We[(size_t)(bn + m) * IN_DIM + (kt + sk)];
        }
        __syncthreads();
#pragma unroll
        for (int kk = 0; kk < 16; ++kk) {
            const float4 xa = *(const float4*)&lx[kk][ty * 8];
            const float4 xb = *(const float4*)&lx[kk][ty * 8 + 4];
            const float4 wa = *(const float4*)&lw[kk][tx * 4];
            const float4 wb = *(const float4*)&lw[kk][tx * 4 + 64];
            const float xf[8] = {xa.x, xa.y, xa.z, xa.w, xb.x, xb.y, xb.z, xb.w};
            const float wf[8] = {wa.x, wa.y, wa.z, wa.w, wb.x, wb.y, wb.z, wb.w};
#pragma unroll
            for (int r = 0; r < 8; ++r)
#pragma unroll
                for (int c = 0; c < 8; ++c)
                    acc[r][c] = fmaf(xf[r], wf[c], acc[r][c]);
        }
    }
#pragma unroll
    for (int r = 0; r < 8; ++r) {
        const size_t row = (size_t)(bm + ty * 8 + r) * HID;
#pragma unroll
        for (int c = 0; c < 4; ++c) {
            h[row + bn + tx * 4 + c]      = fmaxf(acc[r][c]     + be[bn + tx * 4 + c], 0.f);
            h[row + bn + 64 + tx * 4 + c] = fmaxf(acc[r][c + 4] + be[bn + 64 + tx * 4 + c], 0.f);
        }
    }
}

// ---------------- K2: wave-per-row: bisection top-k -> lazy f64 refine -> mask + decode ----------------
// 4 rows / 256-thread block, one wave per row. No LDS histogram, no LDS atomics:
// candidate count via scalar ballots; bisect fp32 keyspace until 24<=n<=64.
__global__ __launch_bounds__(256) void k_topk_decode(
    float* __restrict__ h,
    const float* __restrict__ x,  const float* __restrict__ We,
    const float* __restrict__ be,
    const ushort* __restrict__ WdTb, const float* __restrict__ Wd,
    const float* __restrict__ bd,
    float* __restrict__ recon, const int use_bf)
{
    const int wid  = threadIdx.x >> 6;
    const int lane = threadIdx.x & 63;
    const int b    = blockIdx.x * 4 + wid;
    float* hrow = h + (size_t)b * HID;

    __shared__ float  cvF [4][MAXC];
    __shared__ int    cjL [4][MAXC];
    __shared__ double cvD [4][MAXC];
    __shared__ float  selv[4][KSEL];
    __shared__ int    selj[4][KSEL];

    // ---- load 16 h values per lane (coalesced float4 at element lane*4 + q*256) ----
    float vals[4][4];
    uint  keys[4][4];
#pragma unroll
    for (int q = 0; q < 4; ++q) {
        const float4 v4 = *(const float4*)&hrow[q * 256 + lane * 4];
        vals[q][0] = v4.x; vals[q][1] = v4.y; vals[q][2] = v4.z; vals[q][3] = v4.w;
#pragma unroll
        for (int i = 0; i < 4; ++i) keys[q][i] = __float_as_uint(vals[q][i]); // h>=0 monotone
    }

    // ---- Phase A: bisect threshold T on uint keyspace: 24 <= count(key>=T) <= 64 ----
    uint lo = 0u, hi = 0x7F800000u, T = 0u;
    bool found = false;
    for (int it = 0; it < 32 && !found; ++it) {
        const uint mid = (lo + hi) >> 1;
        int c = 0;
#pragma unroll
        for (int q = 0; q < 4; ++q)
#pragma unroll
            for (int i = 0; i < 4; ++i)
                c += (int)__popcll(__ballot(keys[q][i] >= mid));   // scalar, wave-uniform
        if (c >= TARGET && c <= MAXC) { T = mid; found = true; }
        else if (c > MAXC) lo = mid;
        else hi = mid;
        if (!found && hi - lo <= 1u) { T = lo; found = true; }     // degenerate ties: clamp
    }
    if (!found) T = lo;
    const uint prefix = T;

    // ---- Phase B: compact candidates via shuffle prefix-sum (deterministic order) ----
    uint cnt = 0;
#pragma unroll
    for (int q = 0; q < 4; ++q)
#pragma unroll
        for (int i = 0; i < 4; ++i) cnt += (keys[q][i] >= prefix) ? 1u : 0u;
    uint inc = cnt;
#pragma unroll
    for (int off = 1; off < 64; off <<= 1) {
        const uint o = __shfl_up(inc, off);
        if (lane >= off) inc += o;
    }
    const uint base = inc - cnt;
    const int  n    = min((int)__shfl((int)inc, 63), MAXC);
    {
        uint m = 0;
#pragma unroll
        for (int q = 0; q < 4; ++q)
#pragma unroll
            for (int i = 0; i < 4; ++i)
                if (keys[q][i] >= prefix) {
                    const uint slot = base + m; ++m;
                    if (slot < MAXC) {
                        cvF[wid][slot] = vals[q][i];
                        cjL[wid][slot] = q * 256 + lane * 4 + i;
                    }
                }
    }
    __builtin_amdgcn_wave_barrier();

    // ---- Phase C: fp32 rank via shuffles (one LDS read per lane, then register-only) ----
    const float myv = (lane < n) ? cvF[wid][lane] : -FLT_MAX;
    const int   myj = (lane < n) ? cjL[wid][lane] : 0x7fffffff;
    int rank = 0;
    for (int o = 0; o < n; ++o) {
        const float ov = __shfl(myv, o);
        const int   oj = __shfl(myj, o);
        rank += (ov > myv || (ov == myv && oj < myj)) ? 1 : 0;
    }
    const unsigned long long b19 = __ballot(lane < n && rank == KSEL - 1);
    const unsigned long long b20 = __ballot(lane < n && rank == KSEL);
    const float v20 = b19 ? __shfl(myv, __ffsll(b19) - 1) : 0.f;
    const float v21 = b20 ? __shfl(myv, __ffsll(b20) - 1) : -1e9f;
    const bool  amb = (b20 != 0ull) && (v20 - v21 <= DELTA);

    unsigned long long selm;
    if (!amb) {
        if (lane < n && rank < KSEL) { selv[wid][rank] = myv; selj[wid][rank] = myj; }
        selm = __ballot(lane < n && rank < KSEL);
    } else {
        // slow path: f64 recompute of candidate dots (x via L2), rank in f64
        const float* xr = x + (size_t)b * IN_DIM;
        const int l4 = lane & 3;
#pragma unroll 1
        for (int p = 0; p < 4; ++p) {
            const int c = p * 16 + (lane >> 2);
            if (c < n) {
                const int j = cjL[wid][c];
                const float* wr = We + (size_t)j * IN_DIM;
                double s0 = 0.0, s1 = 0.0, s2 = 0.0, s3 = 0.0;
#pragma unroll 4
                for (int m = 0; m < 48; ++m) {
                    const int k = l4 * 4 + 16 * m;
                    const float4 w4 = *(const float4*)&wr[k];
                    const float4 x4 = *(const float4*)&xr[k];
                    s0 = fma((double)w4.x, (double)x4.x, s0);
                    s1 = fma((double)w4.y, (double)x4.y, s1);
                    s2 = fma((double)w4.z, (double)x4.z, s2);
                    s3 = fma((double)w4.w, (double)x4.w, s3);
                }
                double s = (s0 + s1) + (s2 + s3);
                s += __shfl_xor(s, 1);
                s += __shfl_xor(s, 2);
                if (l4 == 0) {
                    const double v = s + (double)be[j];
                    cvD[wid][c] = v > 0.0 ? v : 0.0;
                }
            }
        }
        __builtin_amdgcn_wave_barrier();
        const double myd = (lane < n) ? cvD[wid][lane] : -1.0;
        int rk = 0;
        for (int o = 0; o < n; ++o) {
            const double ov = __shfl(myd, o);
            const int   oj = __shfl(myj, o);
            rk += (ov > myd || (ov == myd && oj < myj)) ? 1 : 0;
        }
        if (lane < n && rk < KSEL) { selv[wid][rk] = (float)myd; selj[wid][rk] = myj; }
        selm = __ballot(lane < n && rk < KSEL);
    }
    __builtin_amdgcn_wave_barrier();

    // ---- Phase D: masked h write (recompute slot order -> ballot bit test) ----
    {
        uint m = 0;
#pragma unroll
        for (int q = 0; q < 4; ++q) {
            float4 o;
            float ov[4];
#pragma unroll
            for (int i = 0; i < 4; ++i) {
                bool keep = false;
                if (keys[q][i] >= prefix) {
                    const uint slot = base + m; ++m;
                    keep = (slot < MAXC) && ((selm >> slot) & 1ull);
                }
                ov[i] = keep ? vals[q][i] : 0.f;
            }
            o.x = ov[0]; o.y = ov[1]; o.z = ov[2]; o.w = ov[3];
            *(float4*)&hrow[q * 256 + lane * 4] = o;
        }
    }

    // ---- Phase E: sparse decode (bf16 gather table, L2-resident 1.5 MB) ----
    f32x4 a0 = {0.f,0.f,0.f,0.f}, a1 = {0.f,0.f,0.f,0.f}, a2 = {0.f,0.f,0.f,0.f};
    if (use_bf) {
#pragma unroll 4
        for (int s = 0; s < KSEL; ++s) {
            const float v = selv[wid][s];
            const ushort* wr = WdTb + (size_t)selj[wid][s] * IN_DIM;
            const ushort4 w0 = *(const ushort4*)&wr[lane * 4];
            const ushort4 w1 = *(const ushort4*)&wr[lane * 4 + 256];
            const ushort4 w2 = *(const ushort4*)&wr[lane * 4 + 512];
            a0[0] = fmaf(v, __uint_as_float((uint)w0.x << 16), a0[0]);
            a0[1] = fmaf(v, __uint_as_float((uint)w0.y << 16), a0[1]);
            a0[2] = fmaf(v, __uint_as_float((uint)w0.z << 16), a0[2]);
            a0[3] = fmaf(v, __uint_as_float((uint)w0.w << 16), a0[3]);
            a1[0] = fmaf(v, __uint_as_float((uint)w1.x << 16), a1[0]);
            a1[1] = fmaf(v, __uint_as_float((uint)w1.y << 16), a1[1]);
            a1[2] = fmaf(v, __uint_as_float((uint)w1.z << 16), a1[2]);
            a1[3] = fmaf(v, __uint_as_float((uint)w1.w << 16), a1[3]);
            a2[0] = fmaf(v, __uint_as_float((uint)w2.x << 16), a2[0]);
            a2[1] = fmaf(v, __uint_as_float((uint)w2.y << 16), a2[1]);
            a2[2] = fmaf(v, __uint_as_float((uint)w2.z << 16), a2[2]);
            a2[3] = fmaf(v, __uint_as_float((uint)w2.w << 16), a2[3]);
        }
    } else {
        // correctness fallback: strided fp32 gather from Wd
        for (int s = 0; s < KSEL; ++s) {
            const float v = selv[wid][s];
            const int j = selj[wid][s];
#pragma unroll
            for (int i = 0; i < 4; ++i) {
                a0[i] = fmaf(v, Wd[(size_t)(lane * 4 + i) * HID + j], a0[i]);
                a1[i] = fmaf(v, Wd[(size_t)(lane * 4 + i + 256) * HID + j], a1[i]);
                a2[i] = fmaf(v, Wd[(size_t)(lane * 4 + i + 512) * HID + j], a2[i]);
            }
        }
    }
    float* rrow = recon + (size_t)b * IN_DIM;
    const float4 bd0 = *(const float4*)&bd[lane * 4];
    const float4 bd1 = *(const float4*)&bd[lane * 4 + 256];
    const float4 bd2 = *(const float4*)&bd[lane * 4 + 512];
    *(float4*)&rrow[lane * 4]       = (float4){a0[0] + bd0.x, a0[1] + bd0.y, a0[2] + bd0.z, a0[3] + bd0.w};
    *(float4*)&rrow[lane * 4 + 256] = (float4){a1[0] + bd1.x, a1[1] + bd1.y, a1[2] + bd1.z, a1[3] + bd1.w};
    *(float4*)&rrow[lane * 4 + 512] = (float4){a2[0] + bd2.x, a2[1] + bd2.y, a2[2] + bd2.z, a2[3] + bd2.w};
}

extern "C" void kernel_launch(void* const* d_in, const int* in_sizes, int n_in,
                              void* d_out, int out_size, void* d_ws, size_t ws_size,
                              hipStream_t stream)
{
    const float* x  = (const float*)d_in[0];
    const float* We = (const float*)d_in[1];
    const float* be = (const float*)d_in[2];
    const float* Wd = (const float*)d_in[3];
    const float* bd = (const float*)d_in[4];
    const int batch = in_sizes[0] / IN_DIM;   // 65536

    float* recon = (float*)d_out;
    float* h     = (float*)d_out + (size_t)batch * IN_DIM;

    const size_t WDB_BYTES = (size_t)IN_DIM * HID * sizeof(ushort);    // 1.5 MB
    const size_t WH_BYTES  = (size_t)HID * IN_DIM * sizeof(_Float16);  // 1.5 MB
    const size_t XH_BYTES  = (size_t)batch * IN_DIM * sizeof(_Float16);
    ushort*    WdTb = (ushort*)d_ws;
    _Float16*  wh   = (_Float16*)((char*)d_ws + WDB_BYTES);
    _Float16*  xh   = (_Float16*)((char*)d_ws + WDB_BYTES + WH_BYTES);
    const bool have_wdb = (ws_size >= WDB_BYTES);
    const bool mfma_ok  = (ws_size >= WDB_BYTES + WH_BYTES + XH_BYTES) && (batch % 128 == 0);

    if (have_wdb) {
        dim3 g(HID / 32, IN_DIM / 32), blk(32, 8);
        k_prep_wdb<<<g, blk, 0, stream>>>(Wd, WdTb);
    }
    if (mfma_ok) {
        k_split_x<<<(int)(((size_t)batch * IN_DIM / 8) / 256), 256, 0, stream>>>(x, xh);
        k_split_w<<<(HID * IN_DIM / 8) / 256, 256, 0, stream>>>(We, wh);
        dim3 g(HID / 128, batch / 128);
        k_encode_f16<<<g, 256, 0, stream>>>(xh, wh, be, h);
    } else {
        dim3 g(HID / 128, batch / 128);
        k_encode<<<g, 256, 0, stream>>>(x, We, be, h);
    }
    k_topk_decode<<<batch / 4, 256, 0, stream>>>(h, x, We, be, WdTb, Wd, bd, recon,
                                                 have_wdb ? 1 : 0);
}

// Round 7
// 667.062 us; speedup vs baseline: 1.4684x; 1.4684x over previous
//
#include <hip/hip_runtime.h>
#include <cstdint>
#include <cfloat>

#define IN_DIM 768
#define HID    1024
#define KSEL   20
#define MAXC   64
#define TARGET 24
#define WSCALE 4096.0f
#define INV_WSCALE (1.0f / 4096.0f)
#define DELTA  3e-5f

typedef _Float16 f16x8 __attribute__((ext_vector_type(8)));
typedef float    f32x4 __attribute__((ext_vector_type(4)));

__device__ __forceinline__ void gload_lds16(const void* g, void* l) {
    __builtin_amdgcn_global_load_lds(
        (const __attribute__((address_space(1))) uint32_t*)g,
        (__attribute__((address_space(3))) uint32_t*)l, 16, 0, 0);
}

// ---------------- K0: transpose W_dec [768][1024] -> WdTb [1024][768] bf16 (RNE) ----------------
__global__ void k_prep_wdb(const float* __restrict__ Wd, ushort* __restrict__ WdTb) {
    __shared__ float tile[32][33];
    const int j0 = blockIdx.x * 32;       // along HID
    const int i0 = blockIdx.y * 32;       // along IN_DIM
    const int tx = threadIdx.x;
    const int ty = threadIdx.y;
#pragma unroll
    for (int r = 0; r < 4; ++r)
        tile[ty + r * 8][tx] = Wd[(size_t)(i0 + ty + r * 8) * HID + (j0 + tx)];
    __syncthreads();
#pragma unroll
    for (int r = 0; r < 4; ++r) {
        const float v = tile[tx][ty + r * 8];
        uint u = __float_as_uint(v);
        u += 0x7FFFu + ((u >> 16) & 1u);           // round-to-nearest-even
        WdTb[(size_t)(j0 + ty + r * 8) * IN_DIM + (i0 + tx)] = (ushort)(u >> 16);
    }
}

// ---------------- split kernels: fp32 -> fp16 (W scaled by 4096) ----------------
__global__ __launch_bounds__(256) void k_split_x(const float* __restrict__ x,
                                                 _Float16* __restrict__ xh) {
    const size_t base = ((size_t)blockIdx.x * 256 + threadIdx.x) * 8;
    const float4 a = *(const float4*)(x + base);
    const float4 b = *(const float4*)(x + base + 4);
    f16x8 o;
    o[0] = (_Float16)a.x; o[1] = (_Float16)a.y; o[2] = (_Float16)a.z; o[3] = (_Float16)a.w;
    o[4] = (_Float16)b.x; o[5] = (_Float16)b.y; o[6] = (_Float16)b.z; o[7] = (_Float16)b.w;
    *(f16x8*)(xh + base) = o;
}

__global__ __launch_bounds__(256) void k_split_w(const float* __restrict__ w,
                                                 _Float16* __restrict__ wh) {
    const size_t base = ((size_t)blockIdx.x * 256 + threadIdx.x) * 8;
    const float4 a = *(const float4*)(w + base);
    const float4 b = *(const float4*)(w + base + 4);
    f16x8 o;
    o[0] = (_Float16)(a.x * WSCALE); o[1] = (_Float16)(a.y * WSCALE);
    o[2] = (_Float16)(a.z * WSCALE); o[3] = (_Float16)(a.w * WSCALE);
    o[4] = (_Float16)(b.x * WSCALE); o[5] = (_Float16)(b.y * WSCALE);
    o[6] = (_Float16)(b.z * WSCALE); o[7] = (_Float16)(b.w * WSCALE);
    *(f16x8*)(wh + base) = o;
}

// ---------------- K1: fp16 MFMA encode  h = relu((x16 @ w16^T)/4096 + be) ----------------
__global__ __launch_bounds__(256) void k_encode_f16(
    const _Float16* __restrict__ xh, const _Float16* __restrict__ wh,
    const float* __restrict__ be, float* __restrict__ h)
{
    __shared__ _Float16 lA[128 * 64];
    __shared__ _Float16 lB[128 * 64];
    const int t   = threadIdx.x;
    const int wid = t >> 6, l = t & 63;
    const int wm  = (wid >> 1) * 64, wn = (wid & 1) * 64;
    const int bn  = blockIdx.x * 128, bm = blockIdx.y * 128;

    const int lr = l >> 3;
    const int sl = (l & 7) ^ lr;
    const _Float16* gA = xh + (size_t)(bm + wid * 32 + lr) * IN_DIM + sl * 8;
    const _Float16* gB = wh + (size_t)(bn + wid * 32 + lr) * IN_DIM + sl * 8;
    char* la0 = (char*)lA + wid * 32 * 128;
    char* lb0 = (char*)lB + wid * 32 * 128;

    f32x4 acc[4][4];
#pragma unroll
    for (int i = 0; i < 4; ++i)
#pragma unroll
        for (int j = 0; j < 4; ++j) acc[i][j] = (f32x4){0.f, 0.f, 0.f, 0.f};

    const int row16 = l & 15, kb = l >> 4;

    for (int kt = 0; kt < IN_DIM; kt += 64) {
        __syncthreads();
#pragma unroll
        for (int i = 0; i < 4; ++i) {
            gload_lds16(gA + (size_t)i * 8 * IN_DIM + kt, la0 + i * 1024);
            gload_lds16(gB + (size_t)i * 8 * IN_DIM + kt, lb0 + i * 1024);
        }
        __syncthreads();

        f16x8 af[4][2], bf[4][2];
#pragma unroll
        for (int f = 0; f < 4; ++f) {
            const int ra = wm + f * 16 + row16;
            const int pa = kb ^ (ra & 7);
            af[f][0] = *(const f16x8*)((const char*)lA + ra * 128 + pa * 16);
            af[f][1] = *(const f16x8*)((const char*)lA + ra * 128 + (pa ^ 4) * 16);
            const int rb = wn + f * 16 + row16;
            const int pb = kb ^ (rb & 7);
            bf[f][0] = *(const f16x8*)((const char*)lB + rb * 128 + pb * 16);
            bf[f][1] = *(const f16x8*)((const char*)lB + rb * 128 + (pb ^ 4) * 16);
        }
#pragma unroll
        for (int kh = 0; kh < 2; ++kh)
#pragma unroll
            for (int fm = 0; fm < 4; ++fm)
#pragma unroll
                for (int fn = 0; fn < 4; ++fn)
                    acc[fm][fn] = __builtin_amdgcn_mfma_f32_16x16x32_f16(
                        af[fm][kh], bf[fn][kh], acc[fm][fn], 0, 0, 0);
    }

    const int col = l & 15, rg = (l >> 4) * 4;
#pragma unroll
    for (int fn = 0; fn < 4; ++fn) {
        const int n = bn + wn + fn * 16 + col;
        const float bias = be[n];
#pragma unroll
        for (int fm = 0; fm < 4; ++fm) {
            const int m0 = bm + wm + fm * 16 + rg;
#pragma unroll
            for (int q = 0; q < 4; ++q)
                h[(size_t)(m0 + q) * HID + n] = fmaxf(fmaf(acc[fm][fn][q], INV_WSCALE, bias), 0.f);
        }
    }
}

// ---------------- K1-fallback: fp32 encode ----------------
__global__ __launch_bounds__(256, 2) void k_encode(
    const float* __restrict__ x, const float* __restrict__ We,
    const float* __restrict__ be, float* __restrict__ h)
{
    __shared__ float lx[16][132];
    __shared__ float lw[16][132];
    const int t  = threadIdx.x;
    const int tx = t & 15;
    const int ty = t >> 4;
    const int bn = blockIdx.x * 128;
    const int bm = blockIdx.y * 128;

    float acc[8][8];
#pragma unroll
    for (int r = 0; r < 8; ++r)
#pragma unroll
        for (int c = 0; c < 8; ++c) acc[r][c] = 0.f;

    const int sk = t & 15;
    const int sm = t >> 4;

    for (int kt = 0; kt < IN_DIM; kt += 16) {
        __syncthreads();
#pragma unroll
        for (int p = 0; p < 8; ++p) {
            const int m = sm + p * 16;
            lx[sk][m] = x [(size_t)(bm + m) * IN_DIM + (kt + sk)];
            lw[sk][m] = We[(size_t)(bn + m) * IN_DIM + (kt + sk)];
        }
        __syncthreads();
#pragma unroll
        for (int kk = 0; kk < 16; ++kk) {
            const float4 xa = *(const float4*)&lx[kk][ty * 8];
            const float4 xb = *(const float4*)&lx[kk][ty * 8 + 4];
            const float4 wa = *(const float4*)&lw[kk][tx * 4];
            const float4 wb = *(const float4*)&lw[kk][tx * 4 + 64];
            const float xf[8] = {xa.x, xa.y, xa.z, xa.w, xb.x, xb.y, xb.z, xb.w};
            const float wf[8] = {wa.x, wa.y, wa.z, wa.w, wb.x, wb.y, wb.z, wb.w};
#pragma unroll
            for (int r = 0; r < 8; ++r)
#pragma unroll
                for (int c = 0; c < 8; ++c)
                    acc[r][c] = fmaf(xf[r], wf[c], acc[r][c]);
        }
    }
#pragma unroll
    for (int r = 0; r < 8; ++r) {
        const size_t row = (size_t)(bm + ty * 8 + r) * HID;
#pragma unroll
        for (int c = 0; c < 4; ++c) {
            h[row + bn + tx * 4 + c]      = fmaxf(acc[r][c]     + be[bn + tx * 4 + c], 0.f);
            h[row + bn + 64 + tx * 4 + c] = fmaxf(acc[r][c + 4] + be[bn + 64 + tx * 4 + c], 0.f);
        }
    }
}

// ---------------- K2: wave-per-row: seeded ballot-search top-k -> lazy f64 refine -> mask + decode ----------------
// 4 rows / 256-thread block, one wave per row. Threshold T with count(key>=T) in [24,64]
// found by: wave-max seed, first guess 0.55*M (Gaussian order stats put the window at
// [0.45,0.66]*M), then bracket bisection. ~2-4 evals of 16 ballots each; zero LDS atomics.
template<int USE_BF>
__global__ __launch_bounds__(256) void k_topk_decode(
    float* __restrict__ h,
    const float* __restrict__ x,  const float* __restrict__ We,
    const float* __restrict__ be,
    const ushort* __restrict__ WdTb, const float* __restrict__ Wd,
    const float* __restrict__ bd,
    float* __restrict__ recon)
{
    const int wid  = threadIdx.x >> 6;
    const int lane = threadIdx.x & 63;
    const int b    = blockIdx.x * 4 + wid;
    float* hrow = h + (size_t)b * HID;

    __shared__ float  cvF [4][MAXC];
    __shared__ int    cjL [4][MAXC];
    __shared__ double cvD [4][MAXC];
    __shared__ float  selv[4][KSEL];
    __shared__ int    selj[4][KSEL];

    // ---- load 16 h keys per lane (bit patterns; h>=0 so uint order == float order) ----
    uint keys[4][4];
#pragma unroll
    for (int q = 0; q < 4; ++q) {
        const uint4 k4 = *(const uint4*)&hrow[q * 256 + lane * 4];
        keys[q][0] = k4.x; keys[q][1] = k4.y; keys[q][2] = k4.z; keys[q][3] = k4.w;
    }

    // ---- Phase A: seeded threshold search ----
    uint mk = 0;
#pragma unroll
    for (int q = 0; q < 4; ++q)
#pragma unroll
        for (int i = 0; i < 4; ++i) mk = max(mk, keys[q][i]);
#pragma unroll
    for (int off = 1; off < 64; off <<= 1)
        mk = max(mk, (uint)__shfl_xor((int)mk, off));

    uint loT = 0u, hiT = mk;   // invariants: count(>=0)=1024>64; count(>=mk)<24 (statistically)
    uint T  = __float_as_uint(0.55f * __uint_as_float(mk));
    bool found = false;
#pragma unroll 1
    for (int it = 0; it < 20; ++it) {
        int c = 0;
#pragma unroll
        for (int q = 0; q < 4; ++q)
#pragma unroll
            for (int i = 0; i < 4; ++i)
                c += (int)__popcll(__ballot(keys[q][i] >= T));   // scalar, wave-uniform
        if (c >= TARGET && c <= MAXC) { found = true; break; }
        if (c > MAXC) loT = T; else hiT = T;
        if (hiT - loT <= 1u) { T = loT; found = true; break; }   // degenerate ties: never statistically
        T = (loT + hiT) >> 1;                                    // keys < 2^30, no overflow
    }
    if (!found) T = loT;
    const uint prefix = T;

    // ---- Phase B: compact candidates via shuffle prefix-sum (deterministic order) ----
    uint cnt = 0;
#pragma unroll
    for (int q = 0; q < 4; ++q)
#pragma unroll
        for (int i = 0; i < 4; ++i) cnt += (keys[q][i] >= prefix) ? 1u : 0u;
    uint inc = cnt;
#pragma unroll
    for (int off = 1; off < 64; off <<= 1) {
        const uint o = __shfl_up(inc, off);
        if (lane >= off) inc += o;
    }
    const uint base = inc - cnt;
    const int  n    = min((int)__shfl((int)inc, 63), MAXC);
    {
        uint m = 0;
#pragma unroll
        for (int q = 0; q < 4; ++q)
#pragma unroll
            for (int i = 0; i < 4; ++i)
                if (keys[q][i] >= prefix) {
                    const uint slot = base + m; ++m;
                    if (slot < MAXC) {
                        cvF[wid][slot] = __uint_as_float(keys[q][i]);
                        cjL[wid][slot] = q * 256 + lane * 4 + i;
                    }
                }
    }
    __builtin_amdgcn_wave_barrier();

    // ---- Phase C: fp32 rank via shuffles ----
    const float myv = (lane < n) ? cvF[wid][lane] : -FLT_MAX;
    const int   myj = (lane < n) ? cjL[wid][lane] : 0x7fffffff;
    int rank = 0;
    for (int o = 0; o < n; ++o) {
        const float ov = __shfl(myv, o);
        const int   oj = __shfl(myj, o);
        rank += (ov > myv || (ov == myv && oj < myj)) ? 1 : 0;
    }
    const unsigned long long b19 = __ballot(lane < n && rank == KSEL - 1);
    const unsigned long long b20 = __ballot(lane < n && rank == KSEL);
    const float v20 = b19 ? __shfl(myv, __ffsll(b19) - 1) : 0.f;
    const float v21 = b20 ? __shfl(myv, __ffsll(b20) - 1) : -1e9f;
    const bool  amb = (b20 != 0ull) && (v20 - v21 <= DELTA);

    unsigned long long selm;
    if (!amb) {
        if (lane < n && rank < KSEL) { selv[wid][rank] = myv; selj[wid][rank] = myj; }
        selm = __ballot(lane < n && rank < KSEL);
    } else {
        // slow path: f64 recompute of candidate dots (x via L2), rank in f64
        const float* xr = x + (size_t)b * IN_DIM;
        const int l4 = lane & 3;
#pragma unroll 1
        for (int p = 0; p < 4; ++p) {
            const int c = p * 16 + (lane >> 2);
            if (c < n) {
                const int j = cjL[wid][c];
                const float* wr = We + (size_t)j * IN_DIM;
                double s0 = 0.0, s1 = 0.0, s2 = 0.0, s3 = 0.0;
#pragma unroll 4
                for (int m = 0; m < 48; ++m) {
                    const int k = l4 * 4 + 16 * m;
                    const float4 w4 = *(const float4*)&wr[k];
                    const float4 x4 = *(const float4*)&xr[k];
                    s0 = fma((double)w4.x, (double)x4.x, s0);
                    s1 = fma((double)w4.y, (double)x4.y, s1);
                    s2 = fma((double)w4.z, (double)x4.z, s2);
                    s3 = fma((double)w4.w, (double)x4.w, s3);
                }
                double s = (s0 + s1) + (s2 + s3);
                s += __shfl_xor(s, 1);
                s += __shfl_xor(s, 2);
                if (l4 == 0) {
                    const double v = s + (double)be[j];
                    cvD[wid][c] = v > 0.0 ? v : 0.0;
                }
            }
        }
        __builtin_amdgcn_wave_barrier();
        const double myd = (lane < n) ? cvD[wid][lane] : -1.0;
        int rk = 0;
        for (int o = 0; o < n; ++o) {
            const double ov = __shfl(myd, o);
            const int   oj = __shfl(myj, o);
            rk += (ov > myd || (ov == myd && oj < myj)) ? 1 : 0;
        }
        if (lane < n && rk < KSEL) { selv[wid][rk] = (float)myd; selj[wid][rk] = myj; }
        selm = __ballot(lane < n && rk < KSEL);
    }
    __builtin_amdgcn_wave_barrier();

    // ---- Phase D: masked h write (recompute slot order -> ballot bit test) ----
    {
        uint m = 0;
#pragma unroll
        for (int q = 0; q < 4; ++q) {
            float ov[4];
#pragma unroll
            for (int i = 0; i < 4; ++i) {
                bool keep = false;
                if (keys[q][i] >= prefix) {
                    const uint slot = base + m; ++m;
                    keep = (slot < MAXC) && ((selm >> slot) & 1ull);
                }
                ov[i] = keep ? __uint_as_float(keys[q][i]) : 0.f;
            }
            *(float4*)&hrow[q * 256 + lane * 4] = (float4){ov[0], ov[1], ov[2], ov[3]};
        }
    }

    // ---- Phase E: sparse decode ----
    f32x4 a0 = {0.f,0.f,0.f,0.f}, a1 = {0.f,0.f,0.f,0.f}, a2 = {0.f,0.f,0.f,0.f};
    if (USE_BF) {
#pragma unroll 4
        for (int s = 0; s < KSEL; ++s) {
            const float v = selv[wid][s];
            const ushort* wr = WdTb + (size_t)selj[wid][s] * IN_DIM;
            const ushort4 w0 = *(const ushort4*)&wr[lane * 4];
            const ushort4 w1 = *(const ushort4*)&wr[lane * 4 + 256];
            const ushort4 w2 = *(const ushort4*)&wr[lane * 4 + 512];
            a0[0] = fmaf(v, __uint_as_float((uint)w0.x << 16), a0[0]);
            a0[1] = fmaf(v, __uint_as_float((uint)w0.y << 16), a0[1]);
            a0[2] = fmaf(v, __uint_as_float((uint)w0.z << 16), a0[2]);
            a0[3] = fmaf(v, __uint_as_float((uint)w0.w << 16), a0[3]);
            a1[0] = fmaf(v, __uint_as_float((uint)w1.x << 16), a1[0]);
            a1[1] = fmaf(v, __uint_as_float((uint)w1.y << 16), a1[1]);
            a1[2] = fmaf(v, __uint_as_float((uint)w1.z << 16), a1[2]);
            a1[3] = fmaf(v, __uint_as_float((uint)w1.w << 16), a1[3]);
            a2[0] = fmaf(v, __uint_as_float((uint)w2.x << 16), a2[0]);
            a2[1] = fmaf(v, __uint_as_float((uint)w2.y << 16), a2[1]);
            a2[2] = fmaf(v, __uint_as_float((uint)w2.z << 16), a2[2]);
            a2[3] = fmaf(v, __uint_as_float((uint)w2.w << 16), a2[3]);
        }
    } else {
        for (int s = 0; s < KSEL; ++s) {
            const float v = selv[wid][s];
            const int j = selj[wid][s];
#pragma unroll
            for (int i = 0; i < 4; ++i) {
                a0[i] = fmaf(v, Wd[(size_t)(lane * 4 + i) * HID + j], a0[i]);
                a1[i] = fmaf(v, Wd[(size_t)(lane * 4 + i + 256) * HID + j], a1[i]);
                a2[i] = fmaf(v, Wd[(size_t)(lane * 4 + i + 512) * HID + j], a2[i]);
            }
        }
    }
    float* rrow = recon + (size_t)b * IN_DIM;
    const float4 bd0 = *(const float4*)&bd[lane * 4];
    const float4 bd1 = *(const float4*)&bd[lane * 4 + 256];
    const float4 bd2 = *(const float4*)&bd[lane * 4 + 512];
    *(float4*)&rrow[lane * 4]       = (float4){a0[0] + bd0.x, a0[1] + bd0.y, a0[2] + bd0.z, a0[3] + bd0.w};
    *(float4*)&rrow[lane * 4 + 256] = (float4){a1[0] + bd1.x, a1[1] + bd1.y, a1[2] + bd1.z, a1[3] + bd1.w};
    *(float4*)&rrow[lane * 4 + 512] = (float4){a2[0] + bd2.x, a2[1] + bd2.y, a2[2] + bd2.z, a2[3] + bd2.w};
}

extern "C" void kernel_launch(void* const* d_in, const int* in_sizes, int n_in,
                              void* d_out, int out_size, void* d_ws, size_t ws_size,
                              hipStream_t stream)
{
    const float* x  = (const float*)d_in[0];
    const float* We = (const float*)d_in[1];
    const float* be = (const float*)d_in[2];
    const float* Wd = (const float*)d_in[3];
    const float* bd = (const float*)d_in[4];
    const int batch = in_sizes[0] / IN_DIM;   // 65536

    float* recon = (float*)d_out;
    float* h     = (float*)d_out + (size_t)batch * IN_DIM;

    const size_t WDB_BYTES = (size_t)IN_DIM * HID * sizeof(ushort);    // 1.5 MB
    const size_t WH_BYTES  = (size_t)HID * IN_DIM * sizeof(_Float16);  // 1.5 MB
    const size_t XH_BYTES  = (size_t)batch * IN_DIM * sizeof(_Float16);
    ushort*    WdTb = (ushort*)d_ws;
    _Float16*  wh   = (_Float16*)((char*)d_ws + WDB_BYTES);
    _Float16*  xh   = (_Float16*)((char*)d_ws + WDB_BYTES + WH_BYTES);
    const bool have_wdb = (ws_size >= WDB_BYTES);
    const bool mfma_ok  = (ws_size >= WDB_BYTES + WH_BYTES + XH_BYTES) && (batch % 128 == 0);

    if (have_wdb) {
        dim3 g(HID / 32, IN_DIM / 32), blk(32, 8);
        k_prep_wdb<<<g, blk, 0, stream>>>(Wd, WdTb);
    }
    if (mfma_ok) {
        k_split_x<<<(int)(((size_t)batch * IN_DIM / 8) / 256), 256, 0, stream>>>(x, xh);
        k_split_w<<<(HID * IN_DIM / 8) / 256, 256, 0, stream>>>(We, wh);
        dim3 g(HID / 128, batch / 128);
        k_encode_f16<<<g, 256, 0, stream>>>(xh, wh, be, h);
    } else {
        dim3 g(HID / 128, batch / 128);
        k_encode<<<g, 256, 0, stream>>>(x, We, be, h);
    }
    if (have_wdb)
        k_topk_decode<1><<<batch / 4, 256, 0, stream>>>(h, x, We, be, WdTb, Wd, bd, recon);
    else
        k_topk_decode<0><<<batch / 4, 256, 0, stream>>>(h, x, We, be, WdTb, Wd, bd, recon);
}